// Round 4
// baseline (8817.862 us; speedup 1.0000x reference)
//
#include <hip/hip_runtime.h>
#include <math.h>

#define Bb   64
#define Nn   196
#define Cc   384
#define Hh   8
#define HDd  48
#define DFFf 1536
#define MRr  (Bb * Nn)          // 12544 rows

__device__ __forceinline__ float wsum(float v){
#pragma unroll
  for (int o = 32; o; o >>= 1) v += __shfl_xor(v, o, 64);
  return v;
}
__device__ __forceinline__ float wmaxr(float v){
#pragma unroll
  for (int o = 32; o; o >>= 1) v = fmaxf(v, __shfl_xor(v, o, 64));
  return v;
}

// ---------- per-row LN stats over C=384: m[row], rs[row] ----------
__global__ void lnstats_k(const float* __restrict__ A, const float* __restrict__ A2,
                          float* __restrict__ m, float* __restrict__ rs){
  int row  = blockIdx.x;
  int lane = threadIdx.x;
  size_t base = (size_t)row * Cc;
  float x[6];
#pragma unroll
  for (int i = 0; i < 6; ++i){
    int c = lane + 64 * i;
    float v = A[base + c];
    if (A2) v += A2[base + c];
    x[i] = v;
  }
  float s = x[0] + x[1] + x[2] + x[3] + x[4] + x[5];
  s = wsum(s);
  float mm = s * (1.f / Cc);
  float vs = 0.f;
#pragma unroll
  for (int i = 0; i < 6; ++i){ float d = x[i] - mm; vs += d * d; }
  vs = wsum(vs);
  if (lane == 0){
    m[row]  = mm;
    rs[row] = rsqrtf(vs * (1.f / Cc) + 1e-5f);
  }
}

// ---------- GEMM with optional fused LN on A-load and LN-residual epilogue ----------
// A-side: v = A[r,k] (+A2[r,k]); if stm: v = (v-stm[r])*strs[r]*ag[k]+ab[k]
// out[r,c] = act(acc + bias[c]) (+ res[r,c]) (+ LN(r1[r,c]+r2[r,c]; rm,rrs,rg,rb))
// act: 0=none, 1=exact gelu. 64x64 tile, 256 thr, 4x4 acc.
__global__ __launch_bounds__(256) void gemm_k(
    const float* __restrict__ A, int lda, const float* __restrict__ A2,
    const float* __restrict__ stm, const float* __restrict__ strs,
    const float* __restrict__ ag,  const float* __restrict__ ab,
    const float* __restrict__ W, int ldw, const float* __restrict__ bias, int act,
    const float* __restrict__ res, int ldres,
    const float* __restrict__ r1, const float* __restrict__ r2,
    const float* __restrict__ rm, const float* __restrict__ rrs,
    const float* __restrict__ rg, const float* __restrict__ rb,
    float* __restrict__ out, int ldo, int M, int K, int N){
  __shared__ __align__(16) float As[16][68];   // As[k][r] (transposed, padded)
  __shared__ __align__(16) float Ws[16][64];   // Ws[k][n]
  int tid = threadIdx.x;
  int tx = tid & 15, ty = tid >> 4;
  int n0   = blockIdx.x * 64;
  int row0 = blockIdx.y * 64;
  float acc[4][4] = {};
  for (int k0 = 0; k0 < K; k0 += 16){
#pragma unroll
    for (int s2 = 0; s2 < 4; ++s2){
      int e  = tid + s2 * 256;
      int r  = e >> 4, kk = e & 15;
      int row = row0 + r, kg = k0 + kk;
      float v = A[(size_t)row * lda + kg];
      if (A2)  v += A2[(size_t)row * lda + kg];
      if (stm) v = (v - stm[row]) * strs[row] * ag[kg] + ab[kg];
      As[kk][r] = v;
      int kr = e >> 6, nn2 = e & 63;
      Ws[kr][nn2] = W[(size_t)(k0 + kr) * ldw + n0 + nn2];
    }
    __syncthreads();
#pragma unroll
    for (int kk = 0; kk < 16; ++kk){
      const float4 av = *(const float4*)(&As[kk][ty * 4]);
      const float4 wv = *(const float4*)(&Ws[kk][tx * 4]);
      float aa[4] = {av.x, av.y, av.z, av.w};
      float ww[4] = {wv.x, wv.y, wv.z, wv.w};
#pragma unroll
      for (int i = 0; i < 4; ++i)
#pragma unroll
        for (int j = 0; j < 4; ++j)
          acc[i][j] = fmaf(aa[i], ww[j], acc[i][j]);
    }
    __syncthreads();
  }
#pragma unroll
  for (int i = 0; i < 4; ++i){
    int r = row0 + ty * 4 + i;
#pragma unroll
    for (int j = 0; j < 4; ++j){
      int c = n0 + tx * 4 + j;
      float v = acc[i][j];
      if (bias) v += bias[c];
      if (act)  v = 0.5f * v * (1.f + erff(v * 0.70710678118654752f));
      if (res)  v += res[(size_t)r * ldres + c];
      if (r1)   v += (r1[(size_t)r * ldres + c] + r2[(size_t)r * ldres + c] - rm[r]) * rrs[r] * rg[c] + rb[c];
      out[(size_t)r * ldo + c] = v;
    }
  }
}

// ---------- SE gate: gate[b,c] = 1 + sig(fc(mean_n)) + sig(fc(max_n)) ----------
// q: (B*N, rs) with channel c at col c.  w1:(384,24) w2:(24,384)
__global__ void se_k(const float* __restrict__ q, int rs_, const float* __restrict__ w1,
                     const float* __restrict__ w2, float* __restrict__ gate){
  int b = blockIdx.x;
  int tid = threadIdx.x; // 256
  __shared__ float mv[Cc], xv[Cc], hid[2][24];
  for (int c = tid; c < Cc; c += 256){
    const float* p = q + (size_t)b * Nn * rs_ + c;
    float s = 0.f, mx = -INFINITY;
    for (int n = 0; n < Nn; ++n){
      float v = p[(size_t)n * rs_];
      s += v; mx = fmaxf(mx, v);
    }
    mv[c] = s * (1.f / Nn); xv[c] = mx;
  }
  __syncthreads();
  if (tid < 48){
    int vec = tid / 24, j = tid % 24;
    const float* v = vec ? xv : mv;
    float s = 0.f;
    for (int c = 0; c < Cc; ++c) s += v[c] * w1[c * 24 + j];
    hid[vec][j] = fmaxf(s, 0.f);
  }
  __syncthreads();
  for (int c = tid; c < Cc; c += 256){
    float s0 = 0.f, s1 = 0.f;
    for (int j = 0; j < 24; ++j){
      float w = w2[j * Cc + c];
      s0 += hid[0][j] * w; s1 += hid[1][j] * w;
    }
    gate[b * Cc + c] = 1.f + 1.f / (1.f + __expf(-s0)) + 1.f / (1.f + __expf(-s1));
  }
}

// ---------- SA gate: gate[b,n] = 1 + sig(conv5x5([meanC;maxC]) + bias) ----------
__global__ void sa_k(const float* __restrict__ q, int rs_, const float* __restrict__ w,
                     const float* __restrict__ bias, float* __restrict__ gate){
  int b = blockIdx.x;
  int tid = threadIdx.x; // 256
  __shared__ float pm[Nn], px[Nn];
  if (tid < Nn){
    const float* p = q + ((size_t)b * Nn + tid) * rs_;
    float s = 0.f, mx = -INFINITY;
    for (int c = 0; c < Cc; ++c){ float v = p[c]; s += v; mx = fmaxf(mx, v); }
    pm[tid] = s * (1.f / Cc); px[tid] = mx;
  }
  __syncthreads();
  if (tid < Nn){
    int py = tid / 14, pxx = tid % 14;
    float acc = 0.f;
    for (int ky = 0; ky < 5; ++ky){
      int yy = py + ky - 2;
      if (yy < 0 || yy >= 14) continue;
      for (int kx = 0; kx < 5; ++kx){
        int xx = pxx + kx - 2;
        if (xx < 0 || xx >= 14) continue;
        int n2 = yy * 14 + xx;
        acc += pm[n2] * w[ky * 5 + kx] + px[n2] * w[25 + ky * 5 + kx];
      }
    }
    acc += bias[0];
    gate[b * Nn + tid] = 1.f + 1.f / (1.f + __expf(-acc));
  }
}

// ---------- fused attention per (b,h): out = sum_streams softmax(s*q@K^T*SCALE)@V ----------
// q/k/v pointers pre-offset to their slot's col 0; row i of token (b,n) at ((b*N+n)*rs).
// gates (stream-0 only): gate_c[b*C+h*48+d], gate_n[b*N+r]. out: (B*N, C) merged.
__global__ __launch_bounds__(256) void attn_k(
    const float* __restrict__ q1, int q1rs, float sg1,
    const float* __restrict__ q2, int q2rs, float sg2,
    const float* __restrict__ kp, int krs,
    const float* __restrict__ vp, int vrs,
    const float* __restrict__ gate_c, const float* __restrict__ gate_n,
    float* __restrict__ out){
  __shared__ __align__(16) float Kl[Nn][HDd];
  __shared__ __align__(16) float Vl[Nn][HDd];
  __shared__ __align__(16) float ql[4][HDd];
  __shared__ __align__(16) float pl[4][200];
  int bh = blockIdx.x;
  int b = bh >> 3, h = bh & 7;
  int tid = threadIdx.x;
  int w = tid >> 6, lane = tid & 63;
  int hoff = h * HDd;
  for (int e = tid; e < Nn * HDd; e += 256){
    int n = e / HDd, d = e % HDd;
    size_t rr = (size_t)b * Nn + n;
    Kl[n][d] = kp[rr * krs + hoff + d];
    Vl[n][d] = vp[rr * vrs + hoff + d];
  }
  __syncthreads();
  int nstream = q2 ? 2 : 1;
  for (int r = w; r < Nn; r += 4){
    float oacc = 0.f;
    for (int st = 0; st < nstream; ++st){
      const float* qb = st ? q2 : q1;
      int rs_ = st ? q2rs : q1rs;
      float sg = st ? sg2 : sg1;
      if (lane < HDd){
        float qv = qb[((size_t)b * Nn + r) * rs_ + hoff + lane];
        if (st == 0){
          if (gate_c) qv *= gate_c[b * Cc + hoff + lane];
          if (gate_n) qv *= gate_n[b * Nn + r];
        }
        ql[w][lane] = qv * sg;
      }
      __syncthreads();
      float sv[4];
      float lmax = -INFINITY;
      int cnt = (lane < 4) ? 4 : 3;  // k = lane + 64*t < 196
#pragma unroll
      for (int t = 0; t < 4; ++t){
        if (t < cnt){
          int k = lane + t * 64;
          const float4* q4 = (const float4*)ql[w];
          const float4* k4 = (const float4*)Kl[k];
          float s = 0.f;
#pragma unroll
          for (int d4 = 0; d4 < 12; ++d4){
            float4 a = q4[d4], bq = k4[d4];
            s += a.x * bq.x + a.y * bq.y + a.z * bq.z + a.w * bq.w;
          }
          sv[t] = s; lmax = fmaxf(lmax, s);
        }
      }
      lmax = wmaxr(lmax);
      float lsum = 0.f;
#pragma unroll
      for (int t = 0; t < 4; ++t){
        if (t < cnt){
          float p = __expf(sv[t] - lmax);
          lsum += p;
          pl[w][lane + t * 64] = p;
        }
      }
      lsum = wsum(lsum);
      float inv = 1.f / lsum;
      __syncthreads();
      if (lane < HDd){
        float a2 = 0.f;
        for (int k = 0; k < Nn; ++k) a2 += pl[w][k] * Vl[k][lane];
        oacc += inv * a2;
      }
      __syncthreads();
    }
    if (lane < HDd)
      out[((size_t)b * Nn + r) * Cc + hoff + lane] = oacc;
  }
}

extern "C" void kernel_launch(void* const* d_in, const int* in_sizes, int n_in,
                              void* d_out, int out_size, void* d_ws, size_t ws_size,
                              hipStream_t stream){
  const float* src    = (const float*)d_in[0];
  const float* src1   = (const float*)d_in[1];
  const float* lnpg   = (const float*)d_in[2];
  const float* lnpb   = (const float*)d_in[3];
  const float* ln1g   = (const float*)d_in[4];
  const float* ln1b   = (const float*)d_in[5];
  const float* wqkva  = (const float*)d_in[6];
  const float* wproja = (const float*)d_in[7];
  const float* bproja = (const float*)d_in[8];
  const float* sew1   = (const float*)d_in[9];
  const float* sew2   = (const float*)d_in[10];
  const float* saw    = (const float*)d_in[11];
  const float* sab    = (const float*)d_in[12];
  const float* wqkvc  = (const float*)d_in[13];
  const float* wprojc = (const float*)d_in[14];
  const float* bprojc = (const float*)d_in[15];
  const float* w1     = (const float*)d_in[16];
  const float* b1     = (const float*)d_in[17];
  const float* w2     = (const float*)d_in[18];
  const float* b2     = (const float*)d_in[19];
  float* out = (float*)d_out;

  const size_t F = (size_t)Bb * Nn * Cc;      // 4,816,896 floats
  const int MR = MRr;
  const float SCALE = 0.14433756729740643f;   // 48^-0.5

  // workspace layout: 6F + stats + gates  (~110.6 MiB)
  float* ws   = (float*)d_ws;
  float* Qb   = ws;                 // 4F : qkv / MLP-hidden region
  float* S1   = ws + 4 * F;         // 1F
  float* S2   = ws + 5 * F;         // 1F
  float* st1m = ws + 6 * F;  float* st1r = st1m + MR;
  float* st2m = st1m + 2*MR; float* st2r = st1m + 3*MR;
  float* gse  = st1m + 4*MR;        // B*C
  float* gsa  = gse + (size_t)Bb * Cc; // B*N

  // d_out scratch regions (free until their final write)
  float* OX  = out;          // final x
  float* OY  = out + F;      // final y
  float* OXO = out + 2 * F;  // final xo ; also phase-A (qy,ky) staging then xoa
  float* OYO = out + 3 * F;  // final yo ; also yoa

  dim3 blk(256);
  const int GY = MR / 64;    // 196
#define G(N_) dim3((N_) / 64, GY)
  const float* Z = nullptr;

  // ================= phase A =================
  lnstats_k<<<MR, 64, 0, stream>>>(src,  nullptr, st1m, st1r);
  lnstats_k<<<MR, 64, 0, stream>>>(src1, nullptr, st2m, st2r);
  // x: (qx,kx,vx) = LN(src) @ wqkva[:,384:1536]  -> Qb rs=1152 (3F)
  gemm_k<<<G(1152), blk, 0, stream>>>(src, Cc, Z, st1m, st1r, lnpg, lnpb,
      wqkva + 384, 1536, Z, 0, Z, 0, Z, Z, Z, Z, Z, Z, Qb, 1152, MR, Cc, 1152);
  // y: (qy,ky) = LN(src1) @ wqkva[:,384:1152]    -> OXO rs=768 (2F, out-scratch)
  gemm_k<<<G(768), blk, 0, stream>>>(src1, Cc, Z, st2m, st2r, lnpg, lnpb,
      wqkva + 384, 1536, Z, 0, Z, 0, Z, Z, Z, Z, Z, Z, OXO, 768, MR, Cc, 768);
  se_k<<<Bb, 256, 0, stream>>>(Qb, 1152, sew1, sew2, gse);
  sa_k<<<Bb, 256, 0, stream>>>(OXO, 768, saw, sab, gsa);
  // a1: softmax((qx*(1+gse)) kx)*vx -> OX ; a2: softmax((qy*(1+gsa)) ky)*vx -> OY
  attn_k<<<Bb * Hh, 256, 0, stream>>>(Qb, 1152, SCALE, Z, 0, 0.f,
      Qb + 384, 1152, Qb + 768, 1152, gse, Z, OX);
  attn_k<<<Bb * Hh, 256, 0, stream>>>(OXO, 768, SCALE, Z, 0, 0.f,
      OXO + 384, 768, Qb + 768, 1152, Z, gsa, OY);
  // projections
  gemm_k<<<G(384), blk, 0, stream>>>(OX, Cc, Z, Z, Z, Z, Z, wproja, Cc, bproja, 0,
      Z, 0, Z, Z, Z, Z, Z, Z, S1, Cc, MR, Cc, Cc);                    // xa
  gemm_k<<<G(384), blk, 0, stream>>>(OY, Cc, Z, Z, Z, Z, Z, wproja, Cc, bproja, 0,
      Z, 0, Z, Z, Z, Z, Z, Z, S2, Cc, MR, Cc, Cc);                    // ya
  gemm_k<<<G(384), blk, 0, stream>>>(S1, Cc, Z, Z, Z, Z, Z, wproja, Cc, bproja, 0,
      Z, 0, Z, Z, Z, Z, Z, Z, OXO, Cc, MR, Cc, Cc);                   // xoa
  gemm_k<<<G(384), blk, 0, stream>>>(S2, Cc, Z, Z, Z, Z, Z, wproja, Cc, bproja, 0,
      Z, 0, Z, Z, Z, Z, Z, Z, OYO, Cc, MR, Cc, Cc);                   // yoa
  // x_mid = LN1(xa+src) + mlp(LN1(xa+src)) -> S1
  lnstats_k<<<MR, 64, 0, stream>>>(S1, src, st1m, st1r);
  gemm_k<<<G(1536), blk, 0, stream>>>(S1, Cc, src, st1m, st1r, ln1g, ln1b,
      w1, DFFf, b1, 1, Z, 0, Z, Z, Z, Z, Z, Z, Qb, DFFf, MR, Cc, DFFf);
  gemm_k<<<G(384), blk, 0, stream>>>(Qb, DFFf, Z, Z, Z, Z, Z, w2, Cc, b2, 0,
      Z, Cc, S1, src, st1m, st1r, ln1g, ln1b, S1, Cc, MR, DFFf, Cc);
  // y_mid -> S2
  lnstats_k<<<MR, 64, 0, stream>>>(S2, src1, st1m, st1r);
  gemm_k<<<G(1536), blk, 0, stream>>>(S2, Cc, src1, st1m, st1r, ln1g, ln1b,
      w1, DFFf, b1, 1, Z, 0, Z, Z, Z, Z, Z, Z, Qb, DFFf, MR, Cc, DFFf);
  gemm_k<<<G(384), blk, 0, stream>>>(Qb, DFFf, Z, Z, Z, Z, Z, w2, Cc, b2, 0,
      Z, Cc, S2, src1, st1m, st1r, ln1g, ln1b, S2, Cc, MR, DFFf, Cc);
  // xo final = LN1(xoa+src) + mlp(...) -> OXO (in place, per-element)
  lnstats_k<<<MR, 64, 0, stream>>>(OXO, src, st1m, st1r);
  gemm_k<<<G(1536), blk, 0, stream>>>(OXO, Cc, src, st1m, st1r, ln1g, ln1b,
      w1, DFFf, b1, 1, Z, 0, Z, Z, Z, Z, Z, Z, Qb, DFFf, MR, Cc, DFFf);
  gemm_k<<<G(384), blk, 0, stream>>>(Qb, DFFf, Z, Z, Z, Z, Z, w2, Cc, b2, 0,
      Z, Cc, OXO, src, st1m, st1r, ln1g, ln1b, OXO, Cc, MR, DFFf, Cc);
  // yo final -> OYO
  lnstats_k<<<MR, 64, 0, stream>>>(OYO, src1, st1m, st1r);
  gemm_k<<<G(1536), blk, 0, stream>>>(OYO, Cc, src1, st1m, st1r, ln1g, ln1b,
      w1, DFFf, b1, 1, Z, 0, Z, Z, Z, Z, Z, Z, Qb, DFFf, MR, Cc, DFFf);
  gemm_k<<<G(384), blk, 0, stream>>>(Qb, DFFf, Z, Z, Z, Z, Z, w2, Cc, b2, 0,
      Z, Cc, OYO, src1, st1m, st1r, ln1g, ln1b, OYO, Cc, MR, DFFf, Cc);

  // ================= phase B (_dif replaces x,y) =================
  // x qkv (all 4 slots) = LN_pre(x_mid) @ wqkvc -> Qb rs=1536
  lnstats_k<<<MR, 64, 0, stream>>>(S1, nullptr, st1m, st1r);
  gemm_k<<<G(1536), blk, 0, stream>>>(S1, Cc, Z, st1m, st1r, lnpg, lnpb,
      wqkvc, 1536, Z, 0, Z, 0, Z, Z, Z, Z, Z, Z, Qb, 1536, MR, Cc, 1536);
  // y stats; qyo = LN_pre(y_mid) @ wqkvc[:,0:384] -> S1 (x_mid dead)
  lnstats_k<<<MR, 64, 0, stream>>>(S2, nullptr, st2m, st2r);
  gemm_k<<<G(384), blk, 0, stream>>>(S2, Cc, Z, st2m, st2r, lnpg, lnpb,
      wqkvc, 1536, Z, 0, Z, 0, Z, Z, Z, Z, Z, Z, S1, Cc, MR, Cc, Cc);
  // x_dif_raw = [softmax(qx kx) + softmax(-qyo kx)] @ vx -> OX
  attn_k<<<Bb * Hh, 256, 0, stream>>>(Qb + 384, 1536, SCALE, S1, Cc, -SCALE,
      Qb + 768, 1536, Qb + 1152, 1536, Z, Z, OX);
  // (qy,ky) = LN_pre(y_mid) @ wqkvc[:,384:1152] -> Qb cols 384..1152 (overwrite dead qx,kx)
  gemm_k<<<G(768), blk, 0, stream>>>(S2, Cc, Z, st2m, st2r, lnpg, lnpb,
      wqkvc + 384, 1536, Z, 0, Z, 0, Z, Z, Z, Z, Z, Z, Qb + 384, 1536, MR, Cc, 768);
  // y_dif_raw = [softmax(qy ky) + softmax(-qxo ky)] @ vx -> OY
  attn_k<<<Bb * Hh, 256, 0, stream>>>(Qb + 384, 1536, SCALE, Qb, 1536, -SCALE,
      Qb + 768, 1536, Qb + 1152, 1536, Z, Z, OY);
  // projections: x_dif -> S2, y_dif -> S1
  gemm_k<<<G(384), blk, 0, stream>>>(OX, Cc, Z, Z, Z, Z, Z, wprojc, Cc, bprojc, 0,
      Z, 0, Z, Z, Z, Z, Z, Z, S2, Cc, MR, Cc, Cc);
  gemm_k<<<G(384), blk, 0, stream>>>(OY, Cc, Z, Z, Z, Z, Z, wprojc, Cc, bprojc, 0,
      Z, 0, Z, Z, Z, Z, Z, Z, S1, Cc, MR, Cc, Cc);
  // x final = S2 + mlp(S2) -> OX
  gemm_k<<<G(1536), blk, 0, stream>>>(S2, Cc, Z, Z, Z, Z, Z,
      w1, DFFf, b1, 1, Z, 0, Z, Z, Z, Z, Z, Z, Qb, DFFf, MR, Cc, DFFf);
  gemm_k<<<G(384), blk, 0, stream>>>(Qb, DFFf, Z, Z, Z, Z, Z, w2, Cc, b2, 0,
      S2, Cc, Z, Z, Z, Z, Z, Z, OX, Cc, MR, DFFf, Cc);
  // y final = S1 + mlp(S1) -> OY
  gemm_k<<<G(1536), blk, 0, stream>>>(S1, Cc, Z, Z, Z, Z, Z,
      w1, DFFf, b1, 1, Z, 0, Z, Z, Z, Z, Z, Z, Qb, DFFf, MR, Cc, DFFf);
  gemm_k<<<G(384), blk, 0, stream>>>(Qb, DFFf, Z, Z, Z, Z, Z, w2, Cc, b2, 0,
      S1, Cc, Z, Z, Z, Z, Z, Z, OY, Cc, MR, DFFf, Cc);
#undef G
}

// Round 5
// 3284.110 us; speedup vs baseline: 2.6850x; 2.6850x over previous
//
#include <hip/hip_runtime.h>
#include <math.h>

#define Bb   64
#define Nn   196
#define Cc   384
#define Hh   8
#define HDd  48
#define DFFf 1536
#define MRr  (Bb * Nn)          // 12544 rows

typedef __attribute__((ext_vector_type(8))) short bf16x8v;
typedef __attribute__((ext_vector_type(4))) float f32x4v;

__device__ __forceinline__ ushort f2bf(float f){
  union { float f; uint u; } v; v.f = f;
  uint r = v.u + 0x7FFFu + ((v.u >> 16) & 1u);
  return (ushort)(r >> 16);
}
__device__ __forceinline__ float bf2f(ushort u){
  union { uint u; float f; } v; v.u = ((uint)u) << 16;
  return v.f;
}

__device__ __forceinline__ float wsum(float v){
#pragma unroll
  for (int o = 32; o; o >>= 1) v += __shfl_xor(v, o, 64);
  return v;
}
__device__ __forceinline__ float wmaxr(float v){
#pragma unroll
  for (int o = 32; o; o >>= 1) v = fmaxf(v, __shfl_xor(v, o, 64));
  return v;
}

// ---------- per-row LN stats over C=384: m[row], rs[row] ----------
__global__ void lnstats_k(const float* __restrict__ A, const float* __restrict__ A2,
                          float* __restrict__ m, float* __restrict__ rs){
  int row  = blockIdx.x;
  int lane = threadIdx.x;
  size_t base = (size_t)row * Cc;
  float x[6];
#pragma unroll
  for (int i = 0; i < 6; ++i){
    int c = lane + 64 * i;
    float v = A[base + c];
    if (A2) v += A2[base + c];
    x[i] = v;
  }
  float s = x[0] + x[1] + x[2] + x[3] + x[4] + x[5];
  s = wsum(s);
  float mm = s * (1.f / Cc);
  float vs = 0.f;
#pragma unroll
  for (int i = 0; i < 6; ++i){ float d = x[i] - mm; vs += d * d; }
  vs = wsum(vs);
  if (lane == 0){
    m[row]  = mm;
    rs[row] = rsqrtf(vs * (1.f / Cc) + 1e-5f);
  }
}

// ---------- weight convert+transpose: W[K][N] f32 -> WT[N][K] bf16 ----------
__global__ void wconv_k(const float* __restrict__ W, ushort* __restrict__ WT,
                        int K, int N){
  int idx = blockIdx.x * 256 + threadIdx.x;
  if (idx >= K * N) return;
  int k = idx / N, n = idx - k * N;
  WT[(size_t)n * K + k] = f2bf(W[idx]);
}

// ---------- MFMA GEMM: out = act(LN?(A(+A2)) @ W + bias) (+res) (+LN-residual) ----------
// 128x128 tile, BK=64, 256 thr (4 waves 2x2), mfma_f32_16x16x32_bf16.
#define BMm 128
#define BNn 128
#define BKk 64
#define LDK 72   // BK + 8 bf16 pad

__global__ __launch_bounds__(256) void mgemm_k(
    const float* __restrict__ A, int lda, const float* __restrict__ A2,
    const float* __restrict__ stm, const float* __restrict__ strs,
    const float* __restrict__ ag,  const float* __restrict__ ab,
    const ushort* __restrict__ WT, int ldwt, const float* __restrict__ bias, int act,
    const float* __restrict__ res, int ldres,
    const float* __restrict__ r1, const float* __restrict__ r2,
    const float* __restrict__ rm, const float* __restrict__ rrs,
    const float* __restrict__ rg, const float* __restrict__ rb,
    float* __restrict__ out, int ldo, int M, int K, int N){
  __shared__ ushort As[BMm][LDK];
  __shared__ ushort Bs[BNn][LDK];
  const int tid  = threadIdx.x;
  const int lane = tid & 63;
  const int wid  = tid >> 6;
  const int wr = wid >> 1, wc = wid & 1;
  const int row0 = blockIdx.y * BMm;
  const int n0   = blockIdx.x * BNn;

  f32x4v acc[4][4];
#pragma unroll
  for (int m = 0; m < 4; ++m)
#pragma unroll
    for (int n = 0; n < 4; ++n) acc[m][n] = (f32x4v){0.f, 0.f, 0.f, 0.f};

  const int arow = tid >> 4;          // 0..15
  const int akq  = (tid & 15) * 4;    // 0..60
  const int bcol = tid >> 1;          // 0..127
  const int bko  = (tid & 1) * 32;

  for (int k0 = 0; k0 < K; k0 += BKk){
    // stage A (f32 -> optional add/LN -> bf16)
#pragma unroll
    for (int p = 0; p < 8; ++p){
      int r = arow + p * 16;
      int row = row0 + r;
      int kg = k0 + akq;
      float4 v = *(const float4*)&A[(size_t)row * lda + kg];
      if (A2){
        float4 w = *(const float4*)&A2[(size_t)row * lda + kg];
        v.x += w.x; v.y += w.y; v.z += w.z; v.w += w.w;
      }
      if (stm){
        float mm = stm[row], rr = strs[row];
        float4 g  = *(const float4*)&ag[kg];
        float4 bb = *(const float4*)&ab[kg];
        v.x = (v.x - mm) * rr * g.x + bb.x;
        v.y = (v.y - mm) * rr * g.y + bb.y;
        v.z = (v.z - mm) * rr * g.z + bb.z;
        v.w = (v.w - mm) * rr * g.w + bb.w;
      }
      ushort4 o; o.x = f2bf(v.x); o.y = f2bf(v.y); o.z = f2bf(v.z); o.w = f2bf(v.w);
      *(ushort4*)&As[r][akq] = o;
    }
    // stage B: WT bf16 [N][K] row-major -> linear LDS copy
    {
      const ushort* src = &WT[(size_t)(n0 + bcol) * ldwt + k0 + bko];
#pragma unroll
      for (int q = 0; q < 4; ++q)
        *(uint4*)&Bs[bcol][bko + q * 8] = *(const uint4*)(src + q * 8);
    }
    __syncthreads();
#pragma unroll
    for (int ks = 0; ks < 2; ++ks){
      const int kb = ks * 32 + (lane >> 4) * 8;
      bf16x8v af[4], bfm[4];
#pragma unroll
      for (int m = 0; m < 4; ++m)
        af[m] = *(const bf16x8v*)&As[wr * 64 + m * 16 + (lane & 15)][kb];
#pragma unroll
      for (int n = 0; n < 4; ++n)
        bfm[n] = *(const bf16x8v*)&Bs[wc * 64 + n * 16 + (lane & 15)][kb];
#pragma unroll
      for (int m = 0; m < 4; ++m)
#pragma unroll
        for (int n = 0; n < 4; ++n)
          acc[m][n] = __builtin_amdgcn_mfma_f32_16x16x32_bf16(af[m], bfm[n], acc[m][n], 0, 0, 0);
    }
    __syncthreads();
  }
  // epilogue: C/D map col=lane&15, row=(lane>>4)*4+reg  [m89-verified]
  const int rbase = row0 + wr * 64 + (lane >> 4) * 4;
  const int cbase = n0 + wc * 64 + (lane & 15);
#pragma unroll
  for (int m = 0; m < 4; ++m){
#pragma unroll
    for (int n = 0; n < 4; ++n){
      int ccol = cbase + n * 16;
      float bv = bias ? bias[ccol] : 0.f;
#pragma unroll
      for (int j = 0; j < 4; ++j){
        int rr_ = rbase + m * 16 + j;
        float v = acc[m][n][j] + bv;
        if (act) v = 0.5f * v * (1.f + erff(v * 0.70710678118654752f));
        if (res) v += res[(size_t)rr_ * ldres + ccol];
        if (r1)  v += (r1[(size_t)rr_ * ldres + ccol] + r2[(size_t)rr_ * ldres + ccol]
                       - rm[rr_]) * rrs[rr_] * rg[ccol] + rb[ccol];
        out[(size_t)rr_ * ldo + ccol] = v;
      }
    }
  }
}

// ---------- SE gate ----------
__global__ void se_k(const float* __restrict__ q, int rs_, const float* __restrict__ w1,
                     const float* __restrict__ w2, float* __restrict__ gate){
  int b = blockIdx.x;
  int tid = threadIdx.x; // 256
  __shared__ float mv[Cc], xv[Cc], hid[2][24];
  for (int c = tid; c < Cc; c += 256){
    const float* p = q + (size_t)b * Nn * rs_ + c;
    float s = 0.f, mx = -INFINITY;
    for (int n = 0; n < Nn; ++n){
      float v = p[(size_t)n * rs_];
      s += v; mx = fmaxf(mx, v);
    }
    mv[c] = s * (1.f / Nn); xv[c] = mx;
  }
  __syncthreads();
  if (tid < 48){
    int vec = tid / 24, j = tid % 24;
    const float* v = vec ? xv : mv;
    float s = 0.f;
    for (int c = 0; c < Cc; ++c) s += v[c] * w1[c * 24 + j];
    hid[vec][j] = fmaxf(s, 0.f);
  }
  __syncthreads();
  for (int c = tid; c < Cc; c += 256){
    float s0 = 0.f, s1 = 0.f;
    for (int j = 0; j < 24; ++j){
      float w = w2[j * Cc + c];
      s0 += hid[0][j] * w; s1 += hid[1][j] * w;
    }
    gate[b * Cc + c] = 1.f + 1.f / (1.f + __expf(-s0)) + 1.f / (1.f + __expf(-s1));
  }
}

// ---------- SA gate ----------
__global__ void sa_k(const float* __restrict__ q, int rs_, const float* __restrict__ w,
                     const float* __restrict__ bias, float* __restrict__ gate){
  int b = blockIdx.x;
  int tid = threadIdx.x; // 256
  __shared__ float pm[Nn], px[Nn];
  if (tid < Nn){
    const float* p = q + ((size_t)b * Nn + tid) * rs_;
    float s = 0.f, mx = -INFINITY;
    for (int c = 0; c < Cc; ++c){ float v = p[c]; s += v; mx = fmaxf(mx, v); }
    pm[tid] = s * (1.f / Cc); px[tid] = mx;
  }
  __syncthreads();
  if (tid < Nn){
    int py = tid / 14, pxx = tid % 14;
    float acc = 0.f;
    for (int ky = 0; ky < 5; ++ky){
      int yy = py + ky - 2;
      if (yy < 0 || yy >= 14) continue;
      for (int kx = 0; kx < 5; ++kx){
        int xx = pxx + kx - 2;
        if (xx < 0 || xx >= 14) continue;
        int n2 = yy * 14 + xx;
        acc += pm[n2] * w[ky * 5 + kx] + px[n2] * w[25 + ky * 5 + kx];
      }
    }
    acc += bias[0];
    gate[b * Nn + tid] = 1.f + 1.f / (1.f + __expf(-acc));
  }
}

// ---------- fused attention per (b,h), 8 waves, conflict-free LDS ----------
__global__ __launch_bounds__(512) void attn_k(
    const float* __restrict__ q1, int q1rs, float sg1,
    const float* __restrict__ q2, int q2rs, float sg2,
    const float* __restrict__ kp, int krs,
    const float* __restrict__ vp, int vrs,
    const float* __restrict__ gate_c, const float* __restrict__ gate_n,
    float* __restrict__ out){
  __shared__ float  Kt[HDd][256];   // K transposed; cols >=196 zero
  __shared__ ushort Vb[Nn][HDd];    // V in bf16
  __shared__ float  ql[8][HDd];
  __shared__ float  pl[8][200];
  int bh = blockIdx.x, b = bh >> 3, h = bh & 7;
  int tid = threadIdx.x, w = tid >> 6, lane = tid & 63;
  int hoff = h * HDd;
  for (int e = tid; e < 256 * HDd; e += 512){
    int n = e / HDd, d = e - n * HDd;
    float kv = 0.f;
    if (n < Nn){
      size_t rr = (size_t)b * Nn + n;
      kv = kp[rr * krs + hoff + d];
      Vb[n][d] = f2bf(vp[rr * vrs + hoff + d]);
    }
    Kt[d][n] = kv;
  }
  __syncthreads();
  int nstream = q2 ? 2 : 1;
  for (int r = w; r < Nn; r += 8){
    float oacc = 0.f;
    for (int st = 0; st < nstream; ++st){
      const float* qb = st ? q2 : q1;
      int rs_ = st ? q2rs : q1rs;
      float sg = st ? sg2 : sg1;
      if (lane < HDd){
        float qv = qb[((size_t)b * Nn + r) * rs_ + hoff + lane];
        if (st == 0){
          if (gate_c) qv *= gate_c[b * Cc + hoff + lane];
          if (gate_n) qv *= gate_n[b * Nn + r];
        }
        ql[w][lane] = qv * sg;
      }
      // ql/pl are wave-private: no __syncthreads needed in this loop
      float sv0 = 0.f, sv1 = 0.f, sv2 = 0.f, sv3 = 0.f;
#pragma unroll 4
      for (int d = 0; d < HDd; ++d){
        float qd = ql[w][d];
        sv0 = fmaf(qd, Kt[d][lane      ], sv0);
        sv1 = fmaf(qd, Kt[d][lane +  64], sv1);
        sv2 = fmaf(qd, Kt[d][lane + 128], sv2);
        sv3 = fmaf(qd, Kt[d][lane + 192], sv3);
      }
      if (lane >= 4) sv3 = -INFINITY;
      float lmax = wmaxr(fmaxf(fmaxf(sv0, sv1), fmaxf(sv2, sv3)));
      float e0 = __expf(sv0 - lmax), e1 = __expf(sv1 - lmax), e2 = __expf(sv2 - lmax);
      float e3 = (lane < 4) ? __expf(sv3 - lmax) : 0.f;
      float lsum = wsum(e0 + e1 + e2 + e3);
      pl[w][lane] = e0; pl[w][lane + 64] = e1; pl[w][lane + 128] = e2;
      if (lane < 4) pl[w][lane + 192] = e3;
      float inv = 1.f / lsum;
      if (lane < HDd){
        float a2 = 0.f;
        for (int k = 0; k < Nn; k += 4){
          float4 p4 = *(const float4*)&pl[w][k];
          a2 = fmaf(p4.x, bf2f(Vb[k    ][lane]), a2);
          a2 = fmaf(p4.y, bf2f(Vb[k + 1][lane]), a2);
          a2 = fmaf(p4.z, bf2f(Vb[k + 2][lane]), a2);
          a2 = fmaf(p4.w, bf2f(Vb[k + 3][lane]), a2);
        }
        oacc += inv * a2;
      }
    }
    if (lane < HDd)
      out[((size_t)b * Nn + r) * Cc + hoff + lane] = oacc;
  }
}

extern "C" void kernel_launch(void* const* d_in, const int* in_sizes, int n_in,
                              void* d_out, int out_size, void* d_ws, size_t ws_size,
                              hipStream_t stream){
  const float* src    = (const float*)d_in[0];
  const float* src1   = (const float*)d_in[1];
  const float* lnpg   = (const float*)d_in[2];
  const float* lnpb   = (const float*)d_in[3];
  const float* ln1g   = (const float*)d_in[4];
  const float* ln1b   = (const float*)d_in[5];
  const float* wqkva  = (const float*)d_in[6];
  const float* wproja = (const float*)d_in[7];
  const float* bproja = (const float*)d_in[8];
  const float* sew1   = (const float*)d_in[9];
  const float* sew2   = (const float*)d_in[10];
  const float* saw    = (const float*)d_in[11];
  const float* sab    = (const float*)d_in[12];
  const float* wqkvc  = (const float*)d_in[13];
  const float* wprojc = (const float*)d_in[14];
  const float* bprojc = (const float*)d_in[15];
  const float* w1     = (const float*)d_in[16];
  const float* b1     = (const float*)d_in[17];
  const float* w2     = (const float*)d_in[18];
  const float* b2     = (const float*)d_in[19];
  float* out = (float*)d_out;

  const size_t F = (size_t)Bb * Nn * Cc;      // 4,816,896 floats
  const int MR = MRr;
  const float SCALE = 0.14433756729740643f;   // 48^-0.5

  // workspace: 6F f32 + stats/gates + bf16 W^T (~116 MiB total)
  float* ws   = (float*)d_ws;
  float* Qb   = ws;                 // 4F : qkv / MLP-hidden region
  float* S1   = ws + 4 * F;
  float* S2   = ws + 5 * F;
  float* st1m = ws + 6 * F;  float* st1r = st1m + MR;
  float* st2m = st1m + 2 * (size_t)MR; float* st2r = st1m + 3 * (size_t)MR;
  float* gse  = st1m + 4 * (size_t)MR;            // B*C
  float* gsa  = gse + (size_t)Bb * Cc;            // B*N
  ushort* WTa  = (ushort*)(gsa + (size_t)Bb * Nn); // [1536][384]
  ushort* WTc  = WTa + (size_t)1536 * 384;         // [1536][384]
  ushort* WTpa = WTc + (size_t)1536 * 384;         // [384][384]
  ushort* WTpc = WTpa + (size_t)384 * 384;         // [384][384]
  ushort* WT1  = WTpc + (size_t)384 * 384;         // [1536][384]
  ushort* WT2  = WT1 + (size_t)1536 * 384;         // [384][1536]

  float* OX  = out;          // final x
  float* OY  = out + F;      // final y
  float* OXO = out + 2 * F;  // final xo ; scratch before
  float* OYO = out + 3 * F;  // final yo ; scratch before

  dim3 blk(256);
#define G(N_) dim3((N_) / BNn, MRr / BMm)
  const float* Z = nullptr;

  // ---- weight convert+transpose (bf16 W^T) ----
  wconv_k<<<(384 * 1536 + 255) / 256, blk, 0, stream>>>(wqkva, WTa, 384, 1536);
  wconv_k<<<(384 * 1536 + 255) / 256, blk, 0, stream>>>(wqkvc, WTc, 384, 1536);
  wconv_k<<<(384 * 384 + 255) / 256,  blk, 0, stream>>>(wproja, WTpa, 384, 384);
  wconv_k<<<(384 * 384 + 255) / 256,  blk, 0, stream>>>(wprojc, WTpc, 384, 384);
  wconv_k<<<(384 * 1536 + 255) / 256, blk, 0, stream>>>(w1, WT1, 384, 1536);
  wconv_k<<<(1536 * 384 + 255) / 256, blk, 0, stream>>>(w2, WT2, 1536, 384);

  // ================= phase A =================
  lnstats_k<<<MR, 64, 0, stream>>>(src,  nullptr, st1m, st1r);
  lnstats_k<<<MR, 64, 0, stream>>>(src1, nullptr, st2m, st2r);
  // x: (qx,kx,vx) = LN(src) @ wqkva[:,384:1536] -> Qb rs=1152
  mgemm_k<<<G(1152), blk, 0, stream>>>(src, Cc, Z, st1m, st1r, lnpg, lnpb,
      WTa + (size_t)384 * 384, 384, Z, 0, Z, 0, Z, Z, Z, Z, Z, Z, Qb, 1152, MR, Cc, 1152);
  // y: (qy,ky) = LN(src1) @ wqkva[:,384:1152] -> OXO rs=768
  mgemm_k<<<G(768), blk, 0, stream>>>(src1, Cc, Z, st2m, st2r, lnpg, lnpb,
      WTa + (size_t)384 * 384, 384, Z, 0, Z, 0, Z, Z, Z, Z, Z, Z, OXO, 768, MR, Cc, 768);
  se_k<<<Bb, 256, 0, stream>>>(Qb, 1152, sew1, sew2, gse);
  sa_k<<<Bb, 256, 0, stream>>>(OXO, 768, saw, sab, gsa);
  attn_k<<<Bb * Hh, 512, 0, stream>>>(Qb, 1152, SCALE, Z, 0, 0.f,
      Qb + 384, 1152, Qb + 768, 1152, gse, Z, OX);
  attn_k<<<Bb * Hh, 512, 0, stream>>>(OXO, 768, SCALE, Z, 0, 0.f,
      OXO + 384, 768, Qb + 768, 1152, Z, gsa, OY);
  // projections
  mgemm_k<<<G(384), blk, 0, stream>>>(OX, Cc, Z, Z, Z, Z, Z, WTpa, 384, bproja, 0,
      Z, 0, Z, Z, Z, Z, Z, Z, S1, Cc, MR, Cc, Cc);                    // xa
  mgemm_k<<<G(384), blk, 0, stream>>>(OY, Cc, Z, Z, Z, Z, Z, WTpa, 384, bproja, 0,
      Z, 0, Z, Z, Z, Z, Z, Z, S2, Cc, MR, Cc, Cc);                    // ya
  mgemm_k<<<G(384), blk, 0, stream>>>(S1, Cc, Z, Z, Z, Z, Z, WTpa, 384, bproja, 0,
      Z, 0, Z, Z, Z, Z, Z, Z, OXO, Cc, MR, Cc, Cc);                   // xoa
  mgemm_k<<<G(384), blk, 0, stream>>>(S2, Cc, Z, Z, Z, Z, Z, WTpa, 384, bproja, 0,
      Z, 0, Z, Z, Z, Z, Z, Z, OYO, Cc, MR, Cc, Cc);                   // yoa
  // x_mid -> S1
  lnstats_k<<<MR, 64, 0, stream>>>(S1, src, st1m, st1r);
  mgemm_k<<<G(1536), blk, 0, stream>>>(S1, Cc, src, st1m, st1r, ln1g, ln1b,
      WT1, 384, b1, 1, Z, 0, Z, Z, Z, Z, Z, Z, Qb, DFFf, MR, Cc, DFFf);
  mgemm_k<<<G(384), blk, 0, stream>>>(Qb, DFFf, Z, Z, Z, Z, Z, WT2, 1536, b2, 0,
      Z, Cc, S1, src, st1m, st1r, ln1g, ln1b, S1, Cc, MR, DFFf, Cc);
  // y_mid -> S2
  lnstats_k<<<MR, 64, 0, stream>>>(S2, src1, st1m, st1r);
  mgemm_k<<<G(1536), blk, 0, stream>>>(S2, Cc, src1, st1m, st1r, ln1g, ln1b,
      WT1, 384, b1, 1, Z, 0, Z, Z, Z, Z, Z, Z, Qb, DFFf, MR, Cc, DFFf);
  mgemm_k<<<G(384), blk, 0, stream>>>(Qb, DFFf, Z, Z, Z, Z, Z, WT2, 1536, b2, 0,
      Z, Cc, S2, src1, st1m, st1r, ln1g, ln1b, S2, Cc, MR, DFFf, Cc);
  // xo final -> OXO
  lnstats_k<<<MR, 64, 0, stream>>>(OXO, src, st1m, st1r);
  mgemm_k<<<G(1536), blk, 0, stream>>>(OXO, Cc, src, st1m, st1r, ln1g, ln1b,
      WT1, 384, b1, 1, Z, 0, Z, Z, Z, Z, Z, Z, Qb, DFFf, MR, Cc, DFFf);
  mgemm_k<<<G(384), blk, 0, stream>>>(Qb, DFFf, Z, Z, Z, Z, Z, WT2, 1536, b2, 0,
      Z, Cc, OXO, src, st1m, st1r, ln1g, ln1b, OXO, Cc, MR, DFFf, Cc);
  // yo final -> OYO
  lnstats_k<<<MR, 64, 0, stream>>>(OYO, src1, st1m, st1r);
  mgemm_k<<<G(1536), blk, 0, stream>>>(OYO, Cc, src1, st1m, st1r, ln1g, ln1b,
      WT1, 384, b1, 1, Z, 0, Z, Z, Z, Z, Z, Z, Qb, DFFf, MR, Cc, DFFf);
  mgemm_k<<<G(384), blk, 0, stream>>>(Qb, DFFf, Z, Z, Z, Z, Z, WT2, 1536, b2, 0,
      Z, Cc, OYO, src1, st1m, st1r, ln1g, ln1b, OYO, Cc, MR, DFFf, Cc);

  // ================= phase B (_dif replaces x,y) =================
  lnstats_k<<<MR, 64, 0, stream>>>(S1, nullptr, st1m, st1r);
  mgemm_k<<<G(1536), blk, 0, stream>>>(S1, Cc, Z, st1m, st1r, lnpg, lnpb,
      WTc, 384, Z, 0, Z, 0, Z, Z, Z, Z, Z, Z, Qb, 1536, MR, Cc, 1536);
  lnstats_k<<<MR, 64, 0, stream>>>(S2, nullptr, st2m, st2r);
  // qyo = LN(y_mid) @ wqkvc[:,0:384] -> S1 (x_mid dead)
  mgemm_k<<<G(384), blk, 0, stream>>>(S2, Cc, Z, st2m, st2r, lnpg, lnpb,
      WTc, 384, Z, 0, Z, 0, Z, Z, Z, Z, Z, Z, S1, Cc, MR, Cc, Cc);
  // x_dif_raw = [softmax(qx kx) + softmax(-qyo kx)] @ vx -> OX
  attn_k<<<Bb * Hh, 512, 0, stream>>>(Qb + 384, 1536, SCALE, S1, Cc, -SCALE,
      Qb + 768, 1536, Qb + 1152, 1536, Z, Z, OX);
  // (qy,ky) -> Qb cols 384..1152 (overwrite dead qx,kx)
  mgemm_k<<<G(768), blk, 0, stream>>>(S2, Cc, Z, st2m, st2r, lnpg, lnpb,
      WTc + (size_t)384 * 384, 384, Z, 0, Z, 0, Z, Z, Z, Z, Z, Z, Qb + 384, 1536, MR, Cc, 768);
  // y_dif_raw = [softmax(qy ky) + softmax(-qxo ky)] @ vx -> OY
  attn_k<<<Bb * Hh, 512, 0, stream>>>(Qb + 384, 1536, SCALE, Qb, 1536, -SCALE,
      Qb + 768, 1536, Qb + 1152, 1536, Z, Z, OY);
  // projections
  mgemm_k<<<G(384), blk, 0, stream>>>(OX, Cc, Z, Z, Z, Z, Z, WTpc, 384, bprojc, 0,
      Z, 0, Z, Z, Z, Z, Z, Z, S2, Cc, MR, Cc, Cc);
  mgemm_k<<<G(384), blk, 0, stream>>>(OY, Cc, Z, Z, Z, Z, Z, WTpc, 384, bprojc, 0,
      Z, 0, Z, Z, Z, Z, Z, Z, S1, Cc, MR, Cc, Cc);
  // x final = S2 + mlp(S2) -> OX
  mgemm_k<<<G(1536), blk, 0, stream>>>(S2, Cc, Z, Z, Z, Z, Z,
      WT1, 384, b1, 1, Z, 0, Z, Z, Z, Z, Z, Z, Qb, DFFf, MR, Cc, DFFf);
  mgemm_k<<<G(384), blk, 0, stream>>>(Qb, DFFf, Z, Z, Z, Z, Z, WT2, 1536, b2, 0,
      S2, Cc, Z, Z, Z, Z, Z, Z, OX, Cc, MR, DFFf, Cc);
  // y final = S1 + mlp(S1) -> OY
  mgemm_k<<<G(1536), blk, 0, stream>>>(S1, Cc, Z, Z, Z, Z, Z,
      WT1, 384, b1, 1, Z, 0, Z, Z, Z, Z, Z, Z, Qb, DFFf, MR, Cc, DFFf);
  mgemm_k<<<G(384), blk, 0, stream>>>(Qb, DFFf, Z, Z, Z, Z, Z, WT2, 1536, b2, 0,
      S1, Cc, Z, Z, Z, Z, Z, Z, OY, Cc, MR, DFFf, Cc);
#undef G
}

// Round 6
// 2835.249 us; speedup vs baseline: 3.1101x; 1.1583x over previous
//
#include <hip/hip_runtime.h>
#include <math.h>

#define Bb   64
#define Nn   196
#define Cc   384
#define Hh   8
#define HDd  48
#define DFFf 1536
#define MRr  (Bb * Nn)          // 12544 rows

typedef __attribute__((ext_vector_type(8))) short bf16x8v;
typedef __attribute__((ext_vector_type(4))) float f32x4v;

__device__ __forceinline__ ushort f2bf(float f){
  union { float f; uint u; } v; v.f = f;
  uint r = v.u + 0x7FFFu + ((v.u >> 16) & 1u);
  return (ushort)(r >> 16);
}
__device__ __forceinline__ float bf2f(ushort u){
  union { uint u; float f; } v; v.u = ((uint)u) << 16;
  return v.f;
}
__device__ __forceinline__ float ubf_lo(uint u){
  union { uint u; float f; } v; v.u = u << 16; return v.f;
}
__device__ __forceinline__ float ubf_hi(uint u){
  union { uint u; float f; } v; v.u = u & 0xffff0000u; return v.f;
}

__device__ __forceinline__ float wsum(float v){
#pragma unroll
  for (int o = 32; o; o >>= 1) v += __shfl_xor(v, o, 64);
  return v;
}
__device__ __forceinline__ float wmaxr(float v){
#pragma unroll
  for (int o = 32; o; o >>= 1) v = fmaxf(v, __shfl_xor(v, o, 64));
  return v;
}

// ---------- per-row LN stats over C=384: m[row], rs[row] ----------
__global__ void lnstats_k(const float* __restrict__ A, const float* __restrict__ A2,
                          float* __restrict__ m, float* __restrict__ rs){
  int row  = blockIdx.x;
  int lane = threadIdx.x;
  size_t base = (size_t)row * Cc;
  float x[6];
#pragma unroll
  for (int i = 0; i < 6; ++i){
    int c = lane + 64 * i;
    float v = A[base + c];
    if (A2) v += A2[base + c];
    x[i] = v;
  }
  float s = x[0] + x[1] + x[2] + x[3] + x[4] + x[5];
  s = wsum(s);
  float mm = s * (1.f / Cc);
  float vs = 0.f;
#pragma unroll
  for (int i = 0; i < 6; ++i){ float d = x[i] - mm; vs += d * d; }
  vs = wsum(vs);
  if (lane == 0){
    m[row]  = mm;
    rs[row] = rsqrtf(vs * (1.f / Cc) + 1e-5f);
  }
}

// ---------- weight convert+transpose: W[K][N] f32 -> WT[N][K] bf16 ----------
__global__ void wconv_k(const float* __restrict__ W, ushort* __restrict__ WT,
                        int K, int N){
  int idx = blockIdx.x * 256 + threadIdx.x;
  if (idx >= K * N) return;
  int k = idx / N, n = idx - k * N;
  WT[(size_t)n * K + k] = f2bf(W[idx]);
}

// ---------- MFMA GEMM: out = act(LN?(A(+A2)) @ W + bias) (+res) (+LN-residual) ----------
// 128x128 tile, BK=64, 256 thr (4 waves 2x2), mfma_f32_16x16x32_bf16.
#define BMm 128
#define BNn 128
#define BKk 64
#define LDK 72   // BK + 8 bf16 pad

__global__ __launch_bounds__(256) void mgemm_k(
    const float* __restrict__ A, int lda, const float* __restrict__ A2,
    const float* __restrict__ stm, const float* __restrict__ strs,
    const float* __restrict__ ag,  const float* __restrict__ ab,
    const ushort* __restrict__ WT, int ldwt, const float* __restrict__ bias, int act,
    const float* __restrict__ res, int ldres,
    const float* __restrict__ r1, const float* __restrict__ r2,
    const float* __restrict__ rm, const float* __restrict__ rrs,
    const float* __restrict__ rg, const float* __restrict__ rb,
    float* __restrict__ out, int ldo, int M, int K, int N){
  __shared__ ushort As[BMm][LDK];
  __shared__ ushort Bs[BNn][LDK];
  const int tid  = threadIdx.x;
  const int lane = tid & 63;
  const int wid  = tid >> 6;
  const int wr = wid >> 1, wc = wid & 1;
  const int row0 = blockIdx.y * BMm;
  const int n0   = blockIdx.x * BNn;

  f32x4v acc[4][4];
#pragma unroll
  for (int m = 0; m < 4; ++m)
#pragma unroll
    for (int n = 0; n < 4; ++n) acc[m][n] = (f32x4v){0.f, 0.f, 0.f, 0.f};

  const int arow = tid >> 4;          // 0..15
  const int akq  = (tid & 15) * 4;    // 0..60
  const int bcol = tid >> 1;          // 0..127
  const int bko  = (tid & 1) * 32;

  for (int k0 = 0; k0 < K; k0 += BKk){
    // stage A (f32 -> optional add/LN -> bf16)
#pragma unroll
    for (int p = 0; p < 8; ++p){
      int r = arow + p * 16;
      int row = row0 + r;
      int kg = k0 + akq;
      float4 v = *(const float4*)&A[(size_t)row * lda + kg];
      if (A2){
        float4 w = *(const float4*)&A2[(size_t)row * lda + kg];
        v.x += w.x; v.y += w.y; v.z += w.z; v.w += w.w;
      }
      if (stm){
        float mm = stm[row], rr = strs[row];
        float4 g  = *(const float4*)&ag[kg];
        float4 bb = *(const float4*)&ab[kg];
        v.x = (v.x - mm) * rr * g.x + bb.x;
        v.y = (v.y - mm) * rr * g.y + bb.y;
        v.z = (v.z - mm) * rr * g.z + bb.z;
        v.w = (v.w - mm) * rr * g.w + bb.w;
      }
      ushort4 o; o.x = f2bf(v.x); o.y = f2bf(v.y); o.z = f2bf(v.z); o.w = f2bf(v.w);
      *(ushort4*)&As[r][akq] = o;
    }
    // stage B: WT bf16 [N][K] row-major -> linear LDS copy
    {
      const ushort* src = &WT[(size_t)(n0 + bcol) * ldwt + k0 + bko];
#pragma unroll
      for (int q = 0; q < 4; ++q)
        *(uint4*)&Bs[bcol][bko + q * 8] = *(const uint4*)(src + q * 8);
    }
    __syncthreads();
#pragma unroll
    for (int ks = 0; ks < 2; ++ks){
      const int kb = ks * 32 + (lane >> 4) * 8;
      bf16x8v af[4], bfm[4];
#pragma unroll
      for (int m = 0; m < 4; ++m)
        af[m] = *(const bf16x8v*)&As[wr * 64 + m * 16 + (lane & 15)][kb];
#pragma unroll
      for (int n = 0; n < 4; ++n)
        bfm[n] = *(const bf16x8v*)&Bs[wc * 64 + n * 16 + (lane & 15)][kb];
#pragma unroll
      for (int m = 0; m < 4; ++m)
#pragma unroll
        for (int n = 0; n < 4; ++n)
          acc[m][n] = __builtin_amdgcn_mfma_f32_16x16x32_bf16(af[m], bfm[n], acc[m][n], 0, 0, 0);
    }
    __syncthreads();
  }
  // epilogue: C/D map col=lane&15, row=(lane>>4)*4+reg  [m89-verified]
  const int rbase = row0 + wr * 64 + (lane >> 4) * 4;
  const int cbase = n0 + wc * 64 + (lane & 15);
#pragma unroll
  for (int m = 0; m < 4; ++m){
#pragma unroll
    for (int n = 0; n < 4; ++n){
      int ccol = cbase + n * 16;
      float bv = bias ? bias[ccol] : 0.f;
#pragma unroll
      for (int j = 0; j < 4; ++j){
        int rr_ = rbase + m * 16 + j;
        float v = acc[m][n][j] + bv;
        if (act) v = 0.5f * v * (1.f + erff(v * 0.70710678118654752f));
        if (res) v += res[(size_t)rr_ * ldres + ccol];
        if (r1)  v += (r1[(size_t)rr_ * ldres + ccol] + r2[(size_t)rr_ * ldres + ccol]
                       - rm[rr_]) * rrs[rr_] * rg[ccol] + rb[ccol];
        out[(size_t)rr_ * ldo + ccol] = v;
      }
    }
  }
}

// ---------- SE gate ----------
__global__ void se_k(const float* __restrict__ q, int rs_, const float* __restrict__ w1,
                     const float* __restrict__ w2, float* __restrict__ gate){
  int b = blockIdx.x;
  int tid = threadIdx.x; // 256
  __shared__ float mv[Cc], xv[Cc], hid[2][24];
  for (int c = tid; c < Cc; c += 256){
    const float* p = q + (size_t)b * Nn * rs_ + c;
    float s = 0.f, mx = -INFINITY;
    for (int n = 0; n < Nn; ++n){
      float v = p[(size_t)n * rs_];
      s += v; mx = fmaxf(mx, v);
    }
    mv[c] = s * (1.f / Nn); xv[c] = mx;
  }
  __syncthreads();
  if (tid < 48){
    int vec = tid / 24, j = tid % 24;
    const float* v = vec ? xv : mv;
    float s = 0.f;
    for (int c = 0; c < Cc; ++c) s += v[c] * w1[c * 24 + j];
    hid[vec][j] = fmaxf(s, 0.f);
  }
  __syncthreads();
  for (int c = tid; c < Cc; c += 256){
    float s0 = 0.f, s1 = 0.f;
    for (int j = 0; j < 24; ++j){
      float w = w2[j * Cc + c];
      s0 += hid[0][j] * w; s1 += hid[1][j] * w;
    }
    gate[b * Cc + c] = 1.f + 1.f / (1.f + __expf(-s0)) + 1.f / (1.f + __expf(-s1));
  }
}

// ---------- SA gate ----------
__global__ void sa_k(const float* __restrict__ q, int rs_, const float* __restrict__ w,
                     const float* __restrict__ bias, float* __restrict__ gate){
  int b = blockIdx.x;
  int tid = threadIdx.x; // 256
  __shared__ float pm[Nn], px[Nn];
  if (tid < Nn){
    const float* p = q + ((size_t)b * Nn + tid) * rs_;
    float s = 0.f, mx = -INFINITY;
    for (int c = 0; c < Cc; ++c){ float v = p[c]; s += v; mx = fmaxf(mx, v); }
    pm[tid] = s * (1.f / Cc); px[tid] = mx;
  }
  __syncthreads();
  if (tid < Nn){
    int py = tid / 14, pxx = tid % 14;
    float acc = 0.f;
    for (int ky = 0; ky < 5; ++ky){
      int yy = py + ky - 2;
      if (yy < 0 || yy >= 14) continue;
      for (int kx = 0; kx < 5; ++kx){
        int xx = pxx + kx - 2;
        if (xx < 0 || xx >= 14) continue;
        int n2 = yy * 14 + xx;
        acc += pm[n2] * w[ky * 5 + kx] + px[n2] * w[25 + ky * 5 + kx];
      }
    }
    acc += bias[0];
    gate[b * Nn + tid] = 1.f + 1.f / (1.f + __expf(-acc));
  }
}

// ---------- fused attention per (b,h): 4 waves, 4 rows per wave-group ----------
// K packed bf16 pairs; P packed bf16 pairs; V bf16. LDS ~54.7KB -> 2 blocks/CU.
__global__ __launch_bounds__(256) void attn_k(
    const float* __restrict__ q1, int q1rs, float sg1,
    const float* __restrict__ q2, int q2rs, float sg2,
    const float* __restrict__ kp, int krs,
    const float* __restrict__ vp, int vrs,
    const float* __restrict__ gate_c, const float* __restrict__ gate_n,
    float* __restrict__ out){
  __shared__ ushort Ktb[HDd][256];   // K^T bf16, cols >=196 zero
  __shared__ ushort Vb[Nn][HDd];     // V bf16
  __shared__ float  ql[4][4][HDd];   // per-wave 4-row q
  __shared__ uint   plp[4][4][128];  // P bf16-pairs: [j] = (p[2j], p[2j+1])
  int bh = blockIdx.x, b = bh >> 3, h = bh & 7;
  int tid = threadIdx.x, w = tid >> 6, lane = tid & 63;
  int hoff = h * HDd;
  for (int e = tid; e < 256 * HDd; e += 256){
    int n = e / HDd, d = e - n * HDd;
    float kv = 0.f;
    if (n < Nn){
      size_t rr = (size_t)b * Nn + n;
      kv = kp[rr * krs + hoff + d];
      Vb[n][d] = f2bf(vp[rr * vrs + hoff + d]);
    }
    Ktb[d][n] = f2bf(kv);
  }
  __syncthreads();
  const uint* kt32 = (const uint*)Ktb;
  int nstream = q2 ? 2 : 1;
  // cols per lane: c0=2*lane, c1=2*lane+1, c2=128+2*lane, c3=129+2*lane
  const bool c23ok = (lane <= 33);   // cols 128+2*33+1 = 195 max valid
  for (int g = w; g < 49; g += 4){
    int r0 = g * 4;
    float oacc[4] = {0.f, 0.f, 0.f, 0.f};
    for (int st = 0; st < nstream; ++st){
      const float* qb = st ? q2 : q1;
      int rs_ = st ? q2rs : q1rs;
      float sg = st ? sg2 : sg1;
      if (lane < HDd){
#pragma unroll
        for (int ri = 0; ri < 4; ++ri){
          int r = r0 + ri;
          float qv = qb[((size_t)b * Nn + r) * rs_ + hoff + lane];
          if (st == 0){
            if (gate_c) qv *= gate_c[b * Cc + hoff + lane];
            if (gate_n) qv *= gate_n[b * Nn + r];
          }
          ql[w][ri][lane] = qv * sg;
        }
      }
      // wave-private LDS; same pattern as prior green round (no barrier needed)
      float sv[4][4];
#pragma unroll
      for (int ri = 0; ri < 4; ++ri){
        sv[ri][0] = 0.f; sv[ri][1] = 0.f; sv[ri][2] = 0.f; sv[ri][3] = 0.f;
      }
      for (int d = 0; d < HDd; ++d){
        uint ka  = kt32[d * 128 + lane];
        uint kbp = kt32[d * 128 + 64 + lane];
        float kA0 = ubf_lo(ka),  kA1 = ubf_hi(ka);
        float kB0 = ubf_lo(kbp), kB1 = ubf_hi(kbp);
        float q0 = ql[w][0][d], q1v = ql[w][1][d];
        float q2v = ql[w][2][d], q3v = ql[w][3][d];
        sv[0][0] = fmaf(q0, kA0, sv[0][0]); sv[0][1] = fmaf(q0, kA1, sv[0][1]);
        sv[0][2] = fmaf(q0, kB0, sv[0][2]); sv[0][3] = fmaf(q0, kB1, sv[0][3]);
        sv[1][0] = fmaf(q1v, kA0, sv[1][0]); sv[1][1] = fmaf(q1v, kA1, sv[1][1]);
        sv[1][2] = fmaf(q1v, kB0, sv[1][2]); sv[1][3] = fmaf(q1v, kB1, sv[1][3]);
        sv[2][0] = fmaf(q2v, kA0, sv[2][0]); sv[2][1] = fmaf(q2v, kA1, sv[2][1]);
        sv[2][2] = fmaf(q2v, kB0, sv[2][2]); sv[2][3] = fmaf(q2v, kB1, sv[2][3]);
        sv[3][0] = fmaf(q3v, kA0, sv[3][0]); sv[3][1] = fmaf(q3v, kA1, sv[3][1]);
        sv[3][2] = fmaf(q3v, kB0, sv[3][2]); sv[3][3] = fmaf(q3v, kB1, sv[3][3]);
      }
      float inv[4];
#pragma unroll
      for (int ri = 0; ri < 4; ++ri){
        float m01 = fmaxf(sv[ri][0], sv[ri][1]);
        float m23 = c23ok ? fmaxf(sv[ri][2], sv[ri][3]) : -INFINITY;
        float m = wmaxr(fmaxf(m01, m23));
        float e0 = __expf(sv[ri][0] - m);
        float e1 = __expf(sv[ri][1] - m);
        float e2 = c23ok ? __expf(sv[ri][2] - m) : 0.f;
        float e3 = c23ok ? __expf(sv[ri][3] - m) : 0.f;
        float ls = wsum(e0 + e1 + e2 + e3);
        inv[ri] = 1.f / ls;
        plp[w][ri][lane]      = ((uint)f2bf(e0)) | (((uint)f2bf(e1)) << 16);
        plp[w][ri][64 + lane] = ((uint)f2bf(e2)) | (((uint)f2bf(e3)) << 16);
      }
      if (lane < HDd){
        float a0 = 0.f, a1 = 0.f, a2 = 0.f, a3 = 0.f;
        for (int j = 0; j < 98; ++j){   // pair j covers cols 2j, 2j+1 (<=195)
          float v0 = bf2f(Vb[2 * j][lane]);
          float v1 = bf2f(Vb[2 * j + 1][lane]);
          uint p0 = plp[w][0][j], p1 = plp[w][1][j];
          uint p2 = plp[w][2][j], p3 = plp[w][3][j];
          a0 = fmaf(ubf_lo(p0), v0, a0); a0 = fmaf(ubf_hi(p0), v1, a0);
          a1 = fmaf(ubf_lo(p1), v0, a1); a1 = fmaf(ubf_hi(p1), v1, a1);
          a2 = fmaf(ubf_lo(p2), v0, a2); a2 = fmaf(ubf_hi(p2), v1, a2);
          a3 = fmaf(ubf_lo(p3), v0, a3); a3 = fmaf(ubf_hi(p3), v1, a3);
        }
        oacc[0] += inv[0] * a0; oacc[1] += inv[1] * a1;
        oacc[2] += inv[2] * a2; oacc[3] += inv[3] * a3;
      }
    }
    if (lane < HDd){
#pragma unroll
      for (int ri = 0; ri < 4; ++ri)
        out[((size_t)b * Nn + r0 + ri) * Cc + hoff + lane] = oacc[ri];
    }
  }
}

extern "C" void kernel_launch(void* const* d_in, const int* in_sizes, int n_in,
                              void* d_out, int out_size, void* d_ws, size_t ws_size,
                              hipStream_t stream){
  const float* src    = (const float*)d_in[0];
  const float* src1   = (const float*)d_in[1];
  const float* lnpg   = (const float*)d_in[2];
  const float* lnpb   = (const float*)d_in[3];
  const float* ln1g   = (const float*)d_in[4];
  const float* ln1b   = (const float*)d_in[5];
  const float* wqkva  = (const float*)d_in[6];
  const float* wproja = (const float*)d_in[7];
  const float* bproja = (const float*)d_in[8];
  const float* sew1   = (const float*)d_in[9];
  const float* sew2   = (const float*)d_in[10];
  const float* saw    = (const float*)d_in[11];
  const float* sab    = (const float*)d_in[12];
  const float* wqkvc  = (const float*)d_in[13];
  const float* wprojc = (const float*)d_in[14];
  const float* bprojc = (const float*)d_in[15];
  const float* w1     = (const float*)d_in[16];
  const float* b1     = (const float*)d_in[17];
  const float* w2     = (const float*)d_in[18];
  const float* b2     = (const float*)d_in[19];
  float* out = (float*)d_out;

  const size_t F = (size_t)Bb * Nn * Cc;      // 4,816,896 floats
  const int MR = MRr;
  const float SCALE = 0.14433756729740643f;   // 48^-0.5

  // workspace: 6F f32 + stats/gates + bf16 W^T (~116 MiB total)
  float* ws   = (float*)d_ws;
  float* Qb   = ws;                 // 4F : qkv / MLP-hidden region
  float* S1   = ws + 4 * F;
  float* S2   = ws + 5 * F;
  float* st1m = ws + 6 * F;  float* st1r = st1m + MR;
  float* st2m = st1m + 2 * (size_t)MR; float* st2r = st1m + 3 * (size_t)MR;
  float* gse  = st1m + 4 * (size_t)MR;            // B*C
  float* gsa  = gse + (size_t)Bb * Cc;            // B*N
  ushort* WTa  = (ushort*)(gsa + (size_t)Bb * Nn); // [1536][384]
  ushort* WTc  = WTa + (size_t)1536 * 384;         // [1536][384]
  ushort* WTpa = WTc + (size_t)1536 * 384;         // [384][384]
  ushort* WTpc = WTpa + (size_t)384 * 384;         // [384][384]
  ushort* WT1  = WTpc + (size_t)384 * 384;         // [1536][384]
  ushort* WT2  = WT1 + (size_t)1536 * 384;         // [384][1536]

  float* OX  = out;          // final x
  float* OY  = out + F;      // final y
  float* OXO = out + 2 * F;  // final xo ; scratch before
  float* OYO = out + 3 * F;  // final yo ; scratch before

  dim3 blk(256);
#define G(N_) dim3((N_) / BNn, MRr / BMm)
  const float* Z = nullptr;

  // ---- weight convert+transpose (bf16 W^T) ----
  wconv_k<<<(384 * 1536 + 255) / 256, blk, 0, stream>>>(wqkva, WTa, 384, 1536);
  wconv_k<<<(384 * 1536 + 255) / 256, blk, 0, stream>>>(wqkvc, WTc, 384, 1536);
  wconv_k<<<(384 * 384 + 255) / 256,  blk, 0, stream>>>(wproja, WTpa, 384, 384);
  wconv_k<<<(384 * 384 + 255) / 256,  blk, 0, stream>>>(wprojc, WTpc, 384, 384);
  wconv_k<<<(384 * 1536 + 255) / 256, blk, 0, stream>>>(w1, WT1, 384, 1536);
  wconv_k<<<(1536 * 384 + 255) / 256, blk, 0, stream>>>(w2, WT2, 1536, 384);

  // ================= phase A =================
  lnstats_k<<<MR, 64, 0, stream>>>(src,  nullptr, st1m, st1r);
  lnstats_k<<<MR, 64, 0, stream>>>(src1, nullptr, st2m, st2r);
  // x: (qx,kx,vx) = LN(src) @ wqkva[:,384:1536] -> Qb rs=1152
  mgemm_k<<<G(1152), blk, 0, stream>>>(src, Cc, Z, st1m, st1r, lnpg, lnpb,
      WTa + (size_t)384 * 384, 384, Z, 0, Z, 0, Z, Z, Z, Z, Z, Z, Qb, 1152, MR, Cc, 1152);
  // y: (qy,ky) = LN(src1) @ wqkva[:,384:1152] -> OXO rs=768
  mgemm_k<<<G(768), blk, 0, stream>>>(src1, Cc, Z, st2m, st2r, lnpg, lnpb,
      WTa + (size_t)384 * 384, 384, Z, 0, Z, 0, Z, Z, Z, Z, Z, Z, OXO, 768, MR, Cc, 768);
  se_k<<<Bb, 256, 0, stream>>>(Qb, 1152, sew1, sew2, gse);
  sa_k<<<Bb, 256, 0, stream>>>(OXO, 768, saw, sab, gsa);
  attn_k<<<Bb * Hh, 256, 0, stream>>>(Qb, 1152, SCALE, Z, 0, 0.f,
      Qb + 384, 1152, Qb + 768, 1152, gse, Z, OX);
  attn_k<<<Bb * Hh, 256, 0, stream>>>(OXO, 768, SCALE, Z, 0, 0.f,
      OXO + 384, 768, Qb + 768, 1152, Z, gsa, OY);
  // projections
  mgemm_k<<<G(384), blk, 0, stream>>>(OX, Cc, Z, Z, Z, Z, Z, WTpa, 384, bproja, 0,
      Z, 0, Z, Z, Z, Z, Z, Z, S1, Cc, MR, Cc, Cc);                    // xa
  mgemm_k<<<G(384), blk, 0, stream>>>(OY, Cc, Z, Z, Z, Z, Z, WTpa, 384, bproja, 0,
      Z, 0, Z, Z, Z, Z, Z, Z, S2, Cc, MR, Cc, Cc);                    // ya
  mgemm_k<<<G(384), blk, 0, stream>>>(S1, Cc, Z, Z, Z, Z, Z, WTpa, 384, bproja, 0,
      Z, 0, Z, Z, Z, Z, Z, Z, OXO, Cc, MR, Cc, Cc);                   // xoa
  mgemm_k<<<G(384), blk, 0, stream>>>(S2, Cc, Z, Z, Z, Z, Z, WTpa, 384, bproja, 0,
      Z, 0, Z, Z, Z, Z, Z, Z, OYO, Cc, MR, Cc, Cc);                   // yoa
  // x_mid -> S1
  lnstats_k<<<MR, 64, 0, stream>>>(S1, src, st1m, st1r);
  mgemm_k<<<G(1536), blk, 0, stream>>>(S1, Cc, src, st1m, st1r, ln1g, ln1b,
      WT1, 384, b1, 1, Z, 0, Z, Z, Z, Z, Z, Z, Qb, DFFf, MR, Cc, DFFf);
  mgemm_k<<<G(384), blk, 0, stream>>>(Qb, DFFf, Z, Z, Z, Z, Z, WT2, 1536, b2, 0,
      Z, Cc, S1, src, st1m, st1r, ln1g, ln1b, S1, Cc, MR, DFFf, Cc);
  // y_mid -> S2
  lnstats_k<<<MR, 64, 0, stream>>>(S2, src1, st1m, st1r);
  mgemm_k<<<G(1536), blk, 0, stream>>>(S2, Cc, src1, st1m, st1r, ln1g, ln1b,
      WT1, 384, b1, 1, Z, 0, Z, Z, Z, Z, Z, Z, Qb, DFFf, MR, Cc, DFFf);
  mgemm_k<<<G(384), blk, 0, stream>>>(Qb, DFFf, Z, Z, Z, Z, Z, WT2, 1536, b2, 0,
      Z, Cc, S2, src1, st1m, st1r, ln1g, ln1b, S2, Cc, MR, DFFf, Cc);
  // xo final -> OXO
  lnstats_k<<<MR, 64, 0, stream>>>(OXO, src, st1m, st1r);
  mgemm_k<<<G(1536), blk, 0, stream>>>(OXO, Cc, src, st1m, st1r, ln1g, ln1b,
      WT1, 384, b1, 1, Z, 0, Z, Z, Z, Z, Z, Z, Qb, DFFf, MR, Cc, DFFf);
  mgemm_k<<<G(384), blk, 0, stream>>>(Qb, DFFf, Z, Z, Z, Z, Z, WT2, 1536, b2, 0,
      Z, Cc, OXO, src, st1m, st1r, ln1g, ln1b, OXO, Cc, MR, DFFf, Cc);
  // yo final -> OYO
  lnstats_k<<<MR, 64, 0, stream>>>(OYO, src1, st1m, st1r);
  mgemm_k<<<G(1536), blk, 0, stream>>>(OYO, Cc, src1, st1m, st1r, ln1g, ln1b,
      WT1, 384, b1, 1, Z, 0, Z, Z, Z, Z, Z, Z, Qb, DFFf, MR, Cc, DFFf);
  mgemm_k<<<G(384), blk, 0, stream>>>(Qb, DFFf, Z, Z, Z, Z, Z, WT2, 1536, b2, 0,
      Z, Cc, OYO, src1, st1m, st1r, ln1g, ln1b, OYO, Cc, MR, DFFf, Cc);

  // ================= phase B (_dif replaces x,y) =================
  lnstats_k<<<MR, 64, 0, stream>>>(S1, nullptr, st1m, st1r);
  mgemm_k<<<G(1536), blk, 0, stream>>>(S1, Cc, Z, st1m, st1r, lnpg, lnpb,
      WTc, 384, Z, 0, Z, 0, Z, Z, Z, Z, Z, Z, Qb, 1536, MR, Cc, 1536);
  lnstats_k<<<MR, 64, 0, stream>>>(S2, nullptr, st2m, st2r);
  // qyo = LN(y_mid) @ wqkvc[:,0:384] -> S1 (x_mid dead)
  mgemm_k<<<G(384), blk, 0, stream>>>(S2, Cc, Z, st2m, st2r, lnpg, lnpb,
      WTc, 384, Z, 0, Z, 0, Z, Z, Z, Z, Z, Z, S1, Cc, MR, Cc, Cc);
  // x_dif_raw = [softmax(qx kx) + softmax(-qyo kx)] @ vx -> OX
  attn_k<<<Bb * Hh, 256, 0, stream>>>(Qb + 384, 1536, SCALE, S1, Cc, -SCALE,
      Qb + 768, 1536, Qb + 1152, 1536, Z, Z, OX);
  // (qy,ky) -> Qb cols 384..1152 (overwrite dead qx,kx)
  mgemm_k<<<G(768), blk, 0, stream>>>(S2, Cc, Z, st2m, st2r, lnpg, lnpb,
      WTc + (size_t)384 * 384, 384, Z, 0, Z, 0, Z, Z, Z, Z, Z, Z, Qb + 384, 1536, MR, Cc, 768);
  // y_dif_raw = [softmax(qy ky) + softmax(-qxo ky)] @ vx -> OY
  attn_k<<<Bb * Hh, 256, 0, stream>>>(Qb + 384, 1536, SCALE, Qb, 1536, -SCALE,
      Qb + 768, 1536, Qb + 1152, 1536, Z, Z, OY);
  // projections
  mgemm_k<<<G(384), blk, 0, stream>>>(OX, Cc, Z, Z, Z, Z, Z, WTpc, 384, bprojc, 0,
      Z, 0, Z, Z, Z, Z, Z, Z, S2, Cc, MR, Cc, Cc);
  mgemm_k<<<G(384), blk, 0, stream>>>(OY, Cc, Z, Z, Z, Z, Z, WTpc, 384, bprojc, 0,
      Z, 0, Z, Z, Z, Z, Z, Z, S1, Cc, MR, Cc, Cc);
  // x final = S2 + mlp(S2) -> OX
  mgemm_k<<<G(1536), blk, 0, stream>>>(S2, Cc, Z, Z, Z, Z, Z,
      WT1, 384, b1, 1, Z, 0, Z, Z, Z, Z, Z, Z, Qb, DFFf, MR, Cc, DFFf);
  mgemm_k<<<G(384), blk, 0, stream>>>(Qb, DFFf, Z, Z, Z, Z, Z, WT2, 1536, b2, 0,
      S2, Cc, Z, Z, Z, Z, Z, Z, OX, Cc, MR, DFFf, Cc);
  // y final = S1 + mlp(S1) -> OY
  mgemm_k<<<G(1536), blk, 0, stream>>>(S1, Cc, Z, Z, Z, Z, Z,
      WT1, 384, b1, 1, Z, 0, Z, Z, Z, Z, Z, Z, Qb, DFFf, MR, Cc, DFFf);
  mgemm_k<<<G(384), blk, 0, stream>>>(Qb, DFFf, Z, Z, Z, Z, Z, WT2, 1536, b2, 0,
      S1, Cc, Z, Z, Z, Z, Z, Z, OY, Cc, MR, DFFf, Cc);
#undef G
}